// Round 1
// baseline (864.724 us; speedup 1.0000x reference)
//
#include <hip/hip_runtime.h>
#include <math.h>

#define H   256
#define H2  512
#define FRONTIER_BONUS 0.5f
#define LN_EPS   1e-5f
#define F32_EPS  1.1920929e-07f   // jnp.finfo(float32).eps

// ---------------------------------------------------------------------------
// Block-wide reduction helpers (256 threads, shared buffer passed in).
// ---------------------------------------------------------------------------
__device__ __forceinline__ float block_sum_256(float v, float* sbuf) {
    int tid = threadIdx.x;
    sbuf[tid] = v; __syncthreads();
    for (int s = 128; s > 0; s >>= 1) {
        if (tid < s) sbuf[tid] += sbuf[tid + s];
        __syncthreads();
    }
    float r = sbuf[0]; __syncthreads();
    return r;
}

__device__ __forceinline__ float block_max_256(float v, float* sbuf) {
    int tid = threadIdx.x;
    sbuf[tid] = v; __syncthreads();
    for (int s = 128; s > 0; s >>= 1) {
        if (tid < s) sbuf[tid] = fmaxf(sbuf[tid], sbuf[tid + s]);
        __syncthreads();
    }
    float r = sbuf[0]; __syncthreads();
    return r;
}

// ---------------------------------------------------------------------------
// Kernel 1: u = att_vec @ W_edge  (block 0), w = att_vec @ W_query (block 1).
// u[j] = sum_i att_vec[i] * W[i,j] — coalesced across j.
// ---------------------------------------------------------------------------
__global__ __launch_bounds__(H) void k_uw(const float* __restrict__ W_edge,
                                          const float* __restrict__ W_query,
                                          const float* __restrict__ att_vec,
                                          float* __restrict__ u,
                                          float* __restrict__ w) {
    const float* W = (blockIdx.x == 0) ? W_edge : W_query;
    float* dst     = (blockIdx.x == 0) ? u : w;
    int j = threadIdx.x;
    float acc = 0.f;
    #pragma unroll 8
    for (int i = 0; i < H; ++i) acc += att_vec[i] * W[i * H + j];
    dst[j] = acc;
}

// ---------------------------------------------------------------------------
// Kernel 2: qatt[g] = question_tokens[g,:] . w
// ---------------------------------------------------------------------------
__global__ __launch_bounds__(H) void k_qatt(const float* __restrict__ q,
                                            const float* __restrict__ w,
                                            float* __restrict__ qatt) {
    __shared__ float sbuf[256];
    int g = blockIdx.x, tid = threadIdx.x;
    float v = q[(size_t)g * H + tid] * w[tid];
    float s = block_sum_256(v, sbuf);
    if (tid == 0) qatt[g] = s;
}

// ---------------------------------------------------------------------------
// Kernel 3 (dominant): single streaming pass over edge_tokens (512 MB).
// One wave per edge-row: 64 lanes x float4 = 256 floats.
//  - att_raw[e] = leaky(edge_tokens[e].u + qatt[batch[e]]) + 0.5*(!selected)
//  - pooled_sum[g,:] += edge_tokens[e,:]  (edge_batch sorted -> per-wave
//    register accumulator, atomic flush only at graph boundaries)
// ---------------------------------------------------------------------------
__global__ __launch_bounds__(256) void k_main(const float* __restrict__ edge_tokens,
                                              const int*   __restrict__ edge_batch,
                                              const int*   __restrict__ selected,
                                              const float* __restrict__ u,
                                              const float* __restrict__ qatt,
                                              float* __restrict__ att_raw,
                                              float* __restrict__ pooled_sum,
                                              int E, int chunk) {
    int wave = (blockIdx.x * blockDim.x + threadIdx.x) >> 6;
    int lane = threadIdx.x & 63;
    int e0 = wave * chunk;
    if (e0 >= E) return;
    int e1 = e0 + chunk; if (e1 > E) e1 = E;

    const float4 u4 = ((const float4*)u)[lane];
    float4 acc = make_float4(0.f, 0.f, 0.f, 0.f);
    int cur = edge_batch[e0];

    const float4* et = (const float4*)edge_tokens;
    for (int e = e0; e < e1; ++e) {
        int g = edge_batch[e];                     // wave-uniform
        if (g != cur) {                            // flush pooled accumulator
            float* dst = pooled_sum + (size_t)cur * H + lane * 4;
            atomicAdd(dst + 0, acc.x); atomicAdd(dst + 1, acc.y);
            atomicAdd(dst + 2, acc.z); atomicAdd(dst + 3, acc.w);
            acc = make_float4(0.f, 0.f, 0.f, 0.f);
            cur = g;
        }
        float4 t = et[(size_t)e * 64 + lane];
        acc.x += t.x; acc.y += t.y; acc.z += t.z; acc.w += t.w;
        float p = t.x * u4.x + t.y * u4.y + t.z * u4.z + t.w * u4.w;
        #pragma unroll
        for (int off = 32; off > 0; off >>= 1) p += __shfl_down(p, off, 64);
        if (lane == 0) {
            float a = p + qatt[g];
            a = (a > 0.f) ? a : 0.2f * a;          // LeakyReLU(0.2)
            if (selected[e] == 0) a += FRONTIER_BONUS;
            att_raw[e] = a;
        }
    }
    float* dst = pooled_sum + (size_t)cur * H + lane * 4;
    atomicAdd(dst + 0, acc.x); atomicAdd(dst + 1, acc.y);
    atomicAdd(dst + 2, acc.z); atomicAdd(dst + 3, acc.w);
}

// ---------------------------------------------------------------------------
// Kernel 4: per-graph segment softmax -> edge_logits; also emits edge count.
// edge_batch is sorted: binary-search the [s,t) range per graph.
// ---------------------------------------------------------------------------
__global__ __launch_bounds__(256) void k_seg(const int*   __restrict__ edge_batch,
                                             const int*   __restrict__ selected,
                                             const float* __restrict__ att_raw,
                                             float* __restrict__ edge_logits,
                                             int*   __restrict__ gcount,
                                             int E) {
    __shared__ float sbuf[256];
    __shared__ int srange[2];
    int g = blockIdx.x, tid = threadIdx.x;
    if (tid == 0) {
        int lo = 0, hi = E;
        while (lo < hi) { int m = (lo + hi) >> 1; if (edge_batch[m] < g) lo = m + 1; else hi = m; }
        srange[0] = lo;
        hi = E;
        while (lo < hi) { int m = (lo + hi) >> 1; if (edge_batch[m] < g + 1) lo = m + 1; else hi = m; }
        srange[1] = lo;
    }
    __syncthreads();
    int s = srange[0], t = srange[1];

    // pass 1: segment max over ALL edges of the graph
    float m = -INFINITY;
    for (int e = s + tid; e < t; e += 256) m = fmaxf(m, att_raw[e]);
    m = block_max_256(m, sbuf);

    // pass 2: sum of exp over candidate edges
    float ss = 0.f;
    for (int e = s + tid; e < t; e += 256)
        if (selected[e] == 0) ss += expf(att_raw[e] - m);
    ss = block_sum_256(ss, sbuf);
    float denom = fmaxf(ss, F32_EPS);

    // pass 3: write logits
    for (int e = s + tid; e < t; e += 256) {
        float ex = (selected[e] == 0) ? expf(att_raw[e] - m) : 0.f;
        float p  = ex / denom;
        edge_logits[e] = logf(fmaxf(p, F32_EPS));
    }
    if (tid == 0) gcount[g] = t - s;
}

// ---------------------------------------------------------------------------
// Kernel 5: pooled_edges[g,:] = (pooled_sum[g,:] @ W_edge.T) / max(count,1)
// then fused stop head: LayerNorm(concat(P, q)) -> W1 -> GELU -> W2.
// One block per graph, thread i owns output feature i.
// ---------------------------------------------------------------------------
__global__ __launch_bounds__(256) void k_pool(const float* __restrict__ pooled_sum,
                                              const int*   __restrict__ gcount,
                                              const float* __restrict__ q,
                                              const float* __restrict__ W_edge,
                                              const float* __restrict__ ln_g,
                                              const float* __restrict__ ln_b,
                                              const float* __restrict__ W1,
                                              const float* __restrict__ b1,
                                              const float* __restrict__ W2,
                                              const float* __restrict__ b2,
                                              float* __restrict__ pooled_out,
                                              float* __restrict__ stop_out) {
    __shared__ float sS[H];
    __shared__ float sx[H2];
    __shared__ float sxn[H2];
    __shared__ float sbuf[256];
    int g = blockIdx.x, tid = threadIdx.x;

    sS[tid] = pooled_sum[(size_t)g * H + tid];
    __syncthreads();

    int   cnt = gcount[g];
    float inv = 1.f / (float)(cnt > 1 ? cnt : 1);

    // P[i] = (sum_j S[j] * W_edge[i,j]) / denom
    float acc = 0.f;
    const float* wrow = W_edge + (size_t)tid * H;
    #pragma unroll 8
    for (int j = 0; j < H; ++j) acc += sS[j] * wrow[j];
    float P = acc * inv;
    pooled_out[(size_t)g * H + tid] = P;

    sx[tid]     = P;
    sx[tid + H] = q[(size_t)g * H + tid];
    __syncthreads();

    // LayerNorm over 512 (two elements per thread)
    float x0 = sx[tid], x1 = sx[tid + H];
    float mu  = block_sum_256(x0 + x1, sbuf) * (1.f / (float)H2);
    float d0 = x0 - mu, d1 = x1 - mu;
    float var = block_sum_256(d0 * d0 + d1 * d1, sbuf) * (1.f / (float)H2);
    float rstd = rsqrtf(var + LN_EPS);
    sxn[tid]     = d0 * rstd * ln_g[tid]     + ln_b[tid];
    sxn[tid + H] = d1 * rstd * ln_g[tid + H] + ln_b[tid + H];
    __syncthreads();

    // h1[k] = gelu(xn . W1[k,:] + b1[k]);  stop = h1 . W2 + b2
    float a = b1[tid];
    const float* w1r = W1 + (size_t)tid * H2;
    #pragma unroll 8
    for (int j = 0; j < H2; ++j) a += sxn[j] * w1r[j];
    float ge = 0.5f * a * (1.f + erff(a * 0.70710678118654752f));  // exact GELU
    float tot = block_sum_256(ge * W2[tid], sbuf);
    if (tid == 0) stop_out[g] = tot + b2[0];
}

// ---------------------------------------------------------------------------
extern "C" void kernel_launch(void* const* d_in, const int* in_sizes, int n_in,
                              void* d_out, int out_size, void* d_ws, size_t ws_size,
                              hipStream_t stream) {
    const float* edge_tokens     = (const float*)d_in[0];
    const float* question_tokens = (const float*)d_in[1];
    const int*   edge_batch      = (const int*)  d_in[2];
    const int*   selected        = (const int*)  d_in[3];
    const float* W_edge          = (const float*)d_in[4];
    const float* W_query         = (const float*)d_in[5];
    const float* att_vec         = (const float*)d_in[6];
    const float* ln_g            = (const float*)d_in[7];
    const float* ln_b            = (const float*)d_in[8];
    const float* W1              = (const float*)d_in[9];
    const float* b1              = (const float*)d_in[10];
    const float* W2              = (const float*)d_in[11];
    const float* b2              = (const float*)d_in[12];

    const int E = in_sizes[2];          // 500000
    const int G = in_sizes[1] / H;      // 256

    float* out         = (float*)d_out;
    float* edge_logits = out;           // [E]
    float* stop_out    = out + E;       // [G]
    float* pooled_out  = out + E + G;   // [G*H]

    // workspace layout (floats)
    float* ws         = (float*)d_ws;
    float* att_raw    = ws;                              // E
    float* pooled_sum = ws + E;                          // G*H
    float* u          = pooled_sum + (size_t)G * H;      // H
    float* w          = u + H;                           // H
    float* qatt       = w + H;                           // G
    int*   gcount     = (int*)(qatt + G);                // G

    hipMemsetAsync(pooled_sum, 0, (size_t)G * H * sizeof(float), stream);

    k_uw  <<<2, H, 0, stream>>>(W_edge, W_query, att_vec, u, w);
    k_qatt<<<G, H, 0, stream>>>(question_tokens, w, qatt);

    const int nblocks = 1024;                    // 4096 waves, contiguous chunks
    const int waves   = nblocks * (256 / 64);
    const int chunk   = (E + waves - 1) / waves;
    k_main<<<nblocks, 256, 0, stream>>>(edge_tokens, edge_batch, selected,
                                        u, qatt, att_raw, pooled_sum, E, chunk);

    k_seg <<<G, 256, 0, stream>>>(edge_batch, selected, att_raw,
                                  edge_logits, gcount, E);
    k_pool<<<G, 256, 0, stream>>>(pooled_sum, gcount, question_tokens, W_edge,
                                  ln_g, ln_b, W1, b1, W2, b2,
                                  pooled_out, stop_out);
}

// Round 2
// 820.064 us; speedup vs baseline: 1.0545x; 1.0545x over previous
//
#include <hip/hip_runtime.h>
#include <math.h>

#define H   256
#define H2  512
#define FRONTIER_BONUS 0.5f
#define LN_EPS   1e-5f
#define F32_EPS  1.1920929e-07f   // jnp.finfo(float32).eps

// ---------------------------------------------------------------------------
// Block-wide reduction helpers (256 threads).
// ---------------------------------------------------------------------------
__device__ __forceinline__ float block_sum_256(float v, float* sbuf) {
    int tid = threadIdx.x;
    sbuf[tid] = v; __syncthreads();
    for (int s = 128; s > 0; s >>= 1) {
        if (tid < s) sbuf[tid] += sbuf[tid + s];
        __syncthreads();
    }
    float r = sbuf[0]; __syncthreads();
    return r;
}

__device__ __forceinline__ float block_max_256(float v, float* sbuf) {
    int tid = threadIdx.x;
    sbuf[tid] = v; __syncthreads();
    for (int s = 128; s > 0; s >>= 1) {
        if (tid < s) sbuf[tid] = fmaxf(sbuf[tid], sbuf[tid + s]);
        __syncthreads();
    }
    float r = sbuf[0]; __syncthreads();
    return r;
}

__device__ __forceinline__ float wave_sum(float p) {
    #pragma unroll
    for (int off = 1; off < 64; off <<= 1) p += __shfl_xor(p, off, 64);
    return p;   // all lanes hold the total
}

// ---------------------------------------------------------------------------
// Kernel 1: u = att_vec @ W_edge (block 0), w = att_vec @ W_query (block 1).
// ---------------------------------------------------------------------------
__global__ __launch_bounds__(H) void k_uw(const float* __restrict__ W_edge,
                                          const float* __restrict__ W_query,
                                          const float* __restrict__ att_vec,
                                          float* __restrict__ u,
                                          float* __restrict__ w) {
    const float* W = (blockIdx.x == 0) ? W_edge : W_query;
    float* dst     = (blockIdx.x == 0) ? u : w;
    int j = threadIdx.x;
    float acc = 0.f;
    #pragma unroll 8
    for (int i = 0; i < H; ++i) acc += att_vec[i] * W[i * H + j];
    dst[j] = acc;
}

// ---------------------------------------------------------------------------
// Kernel 2: qatt[g] = question_tokens[g,:] . w ; also zero pooled_sum[g,:].
// ---------------------------------------------------------------------------
__global__ __launch_bounds__(H) void k_qatt(const float* __restrict__ q,
                                            const float* __restrict__ w,
                                            float* __restrict__ qatt,
                                            float* __restrict__ pooled_sum) {
    __shared__ float sbuf[256];
    int g = blockIdx.x, tid = threadIdx.x;
    pooled_sum[(size_t)g * H + tid] = 0.f;     // replaces hipMemsetAsync
    float v = q[(size_t)g * H + tid] * w[tid];
    float s = block_sum_256(v, sbuf);
    if (tid == 0) qatt[g] = s;
}

// ---------------------------------------------------------------------------
// Kernel 3 (dominant): one streaming pass over edge_tokens (512 MB).
// One wave per contiguous edge chunk. Branch-free runs of <=64 edges:
// lanes inspect the next 64 edge_batch values, __ballot finds the graph
// boundary, inner loop is unrollable (loads pipeline), butterfly shfl gives
// every lane the row-dot so att_raw writes coalesce (lane i owns edge e+i).
// ---------------------------------------------------------------------------
__global__ __launch_bounds__(256) void k_main(const float* __restrict__ edge_tokens,
                                              const int*   __restrict__ edge_batch,
                                              const int*   __restrict__ selected,
                                              const float* __restrict__ u,
                                              const float* __restrict__ qatt,
                                              float* __restrict__ att_raw,
                                              float* __restrict__ pooled_sum,
                                              int E, int chunk) {
    int wave = (blockIdx.x * blockDim.x + threadIdx.x) >> 6;
    int lane = threadIdx.x & 63;
    int e0 = wave * chunk;
    if (e0 >= E) return;
    int e1 = e0 + chunk; if (e1 > E) e1 = E;

    const float4 u4 = ((const float4*)u)[lane];
    const float4* et = (const float4*)edge_tokens;
    float4 acc = make_float4(0.f, 0.f, 0.f, 0.f);
    int cur = edge_batch[e0];

    int e = e0;
    while (e < e1) {
        int n = e1 - e; if (n > 64) n = 64;
        int idx = e + ((lane < n) ? lane : (n - 1));
        int gb  = edge_batch[idx];                 // coalesced window load
        int sel = selected[idx];
        int g0  = __shfl(gb, 0, 64);               // wave-uniform graph id
        unsigned long long diff = __ballot(gb != g0);
        int run = n;
        if (diff) { int f = (int)__ffsll(diff) - 1; if (f < run) run = f; }

        if (g0 != cur) {                           // flush pooled accumulator
            float* dst = pooled_sum + (size_t)cur * H + lane * 4;
            atomicAdd(dst + 0, acc.x); atomicAdd(dst + 1, acc.y);
            atomicAdd(dst + 2, acc.z); atomicAdd(dst + 3, acc.w);
            acc = make_float4(0.f, 0.f, 0.f, 0.f);
            cur = g0;
        }
        float qa = qatt[g0];                       // wave-uniform
        float my_att = 0.f;

        #pragma unroll 4
        for (int i = 0; i < run; ++i) {
            float4 t = et[(size_t)(e + i) * 64 + lane];
            acc.x += t.x; acc.y += t.y; acc.z += t.z; acc.w += t.w;
            float p = fmaf(t.x, u4.x, fmaf(t.y, u4.y, fmaf(t.z, u4.z, t.w * u4.w)));
            p = wave_sum(p);
            if (i == lane) my_att = p;             // lane i keeps edge e+i
        }

        if (lane < run) {                          // coalesced att_raw store
            float a = my_att + qa;
            a = (a > 0.f) ? a : 0.2f * a;          // LeakyReLU(0.2)
            if (sel == 0) a += FRONTIER_BONUS;
            att_raw[e + lane] = a;
        }
        e += run;
    }
    float* dst = pooled_sum + (size_t)cur * H + lane * 4;
    atomicAdd(dst + 0, acc.x); atomicAdd(dst + 1, acc.y);
    atomicAdd(dst + 2, acc.z); atomicAdd(dst + 3, acc.w);
}

// ---------------------------------------------------------------------------
// Kernel 4: per-graph segment softmax -> edge_logits; also edge count.
// ---------------------------------------------------------------------------
__global__ __launch_bounds__(256) void k_seg(const int*   __restrict__ edge_batch,
                                             const int*   __restrict__ selected,
                                             const float* __restrict__ att_raw,
                                             float* __restrict__ edge_logits,
                                             int*   __restrict__ gcount,
                                             int E) {
    __shared__ float sbuf[256];
    __shared__ int srange[2];
    int g = blockIdx.x, tid = threadIdx.x;
    if (tid == 0) {
        int lo = 0, hi = E;
        while (lo < hi) { int m = (lo + hi) >> 1; if (edge_batch[m] < g) lo = m + 1; else hi = m; }
        srange[0] = lo;
        hi = E;
        while (lo < hi) { int m = (lo + hi) >> 1; if (edge_batch[m] < g + 1) lo = m + 1; else hi = m; }
        srange[1] = lo;
    }
    __syncthreads();
    int s = srange[0], t = srange[1];

    float m = -INFINITY;
    for (int e = s + tid; e < t; e += 256) m = fmaxf(m, att_raw[e]);
    m = block_max_256(m, sbuf);

    float ss = 0.f;
    for (int e = s + tid; e < t; e += 256)
        if (selected[e] == 0) ss += expf(att_raw[e] - m);
    ss = block_sum_256(ss, sbuf);
    float denom = fmaxf(ss, F32_EPS);

    for (int e = s + tid; e < t; e += 256) {
        float ex = (selected[e] == 0) ? expf(att_raw[e] - m) : 0.f;
        float p  = ex / denom;
        edge_logits[e] = logf(fmaxf(p, F32_EPS));
    }
    if (tid == 0) gcount[g] = t - s;
}

// ---------------------------------------------------------------------------
// Kernel 5: pooled_edges[g,:] = (pooled_sum[g,:] @ W_edge.T)/max(cnt,1),
// then LayerNorm(concat(P,q)) -> W1 -> GELU -> W2. Wave-per-output-row so
// every weight load is a coalesced float4 row read (was: stride-1KB/thread).
// ---------------------------------------------------------------------------
__global__ __launch_bounds__(256) void k_pool(const float* __restrict__ pooled_sum,
                                              const int*   __restrict__ gcount,
                                              const float* __restrict__ q,
                                              const float* __restrict__ W_edge,
                                              const float* __restrict__ ln_g,
                                              const float* __restrict__ ln_b,
                                              const float* __restrict__ W1,
                                              const float* __restrict__ b1,
                                              const float* __restrict__ W2,
                                              const float* __restrict__ b2,
                                              float* __restrict__ pooled_out,
                                              float* __restrict__ stop_out) {
    __shared__ __align__(16) float sS[H];
    __shared__ __align__(16) float sP[H];
    __shared__ __align__(16) float sxn[H2];
    __shared__ __align__(16) float sgk[H];
    __shared__ float sbuf[256];
    int g = blockIdx.x, tid = threadIdx.x;
    int lane = tid & 63, wv = tid >> 6;            // 4 waves

    sS[tid] = pooled_sum[(size_t)g * H + tid];
    __syncthreads();
    int   cnt = gcount[g];
    float inv = 1.f / (float)(cnt > 1 ? cnt : 1);

    // Phase 1: P[i] = (sS . W_edge[i,:]) * inv — wave wv owns rows wv*64..+63
    float4 s4 = ((const float4*)sS)[lane];
    for (int r = 0; r < 64; ++r) {
        int i = wv * 64 + r;
        float4 w4 = ((const float4*)(W_edge + (size_t)i * H))[lane];
        float p = fmaf(w4.x, s4.x, fmaf(w4.y, s4.y, fmaf(w4.z, s4.z, w4.w * s4.w)));
        p = wave_sum(p);
        if (lane == 0) sP[i] = p * inv;
    }
    __syncthreads();
    float P = sP[tid];
    pooled_out[(size_t)g * H + tid] = P;

    // Phase 2: LayerNorm over concat(P, q) (512 elems, 2 per thread)
    float x1 = q[(size_t)g * H + tid];
    float mu  = block_sum_256(P + x1, sbuf) * (1.f / (float)H2);
    float d0 = P - mu, d1 = x1 - mu;
    float var = block_sum_256(d0 * d0 + d1 * d1, sbuf) * (1.f / (float)H2);
    float rstd = rsqrtf(var + LN_EPS);
    sxn[tid]     = d0 * rstd * ln_g[tid]     + ln_b[tid];
    sxn[tid + H] = d1 * rstd * ln_g[tid + H] + ln_b[tid + H];
    __syncthreads();

    // Phase 3: h1[k] = gelu(xn . W1[k,:] + b1[k]); stop = sum_k h1[k]*W2[k]
    float4 xa = ((const float4*)sxn)[lane];
    float4 xb = ((const float4*)sxn)[lane + 64];
    for (int r = 0; r < 64; ++r) {
        int k = wv * 64 + r;
        const float4* w1r = (const float4*)(W1 + (size_t)k * H2);
        float4 a0 = w1r[lane], a1 = w1r[lane + 64];
        float p = fmaf(a0.x, xa.x, fmaf(a0.y, xa.y, fmaf(a0.z, xa.z, a0.w * xa.w)))
                + fmaf(a1.x, xb.x, fmaf(a1.y, xb.y, fmaf(a1.z, xb.z, a1.w * xb.w)));
        p = wave_sum(p);
        if (lane == 0) {
            float a = p + b1[k];
            float ge = 0.5f * a * (1.f + erff(a * 0.70710678118654752f));
            sgk[k] = ge * W2[k];
        }
    }
    __syncthreads();
    float tot = block_sum_256(sgk[tid], sbuf);
    if (tid == 0) stop_out[g] = tot + b2[0];
}

// ---------------------------------------------------------------------------
extern "C" void kernel_launch(void* const* d_in, const int* in_sizes, int n_in,
                              void* d_out, int out_size, void* d_ws, size_t ws_size,
                              hipStream_t stream) {
    const float* edge_tokens     = (const float*)d_in[0];
    const float* question_tokens = (const float*)d_in[1];
    const int*   edge_batch      = (const int*)  d_in[2];
    const int*   selected        = (const int*)  d_in[3];
    const float* W_edge          = (const float*)d_in[4];
    const float* W_query         = (const float*)d_in[5];
    const float* att_vec         = (const float*)d_in[6];
    const float* ln_g            = (const float*)d_in[7];
    const float* ln_b            = (const float*)d_in[8];
    const float* W1              = (const float*)d_in[9];
    const float* b1              = (const float*)d_in[10];
    const float* W2              = (const float*)d_in[11];
    const float* b2              = (const float*)d_in[12];

    const int E = in_sizes[2];          // 500000
    const int G = in_sizes[1] / H;      // 256

    float* out         = (float*)d_out;
    float* edge_logits = out;           // [E]
    float* stop_out    = out + E;       // [G]
    float* pooled_out  = out + E + G;   // [G*H]

    float* ws         = (float*)d_ws;
    float* att_raw    = ws;                              // E
    float* pooled_sum = ws + E;                          // G*H
    float* u          = pooled_sum + (size_t)G * H;      // H
    float* w          = u + H;                           // H
    float* qatt       = w + H;                           // G
    int*   gcount     = (int*)(qatt + G);                // G

    k_uw  <<<2, H, 0, stream>>>(W_edge, W_query, att_vec, u, w);
    k_qatt<<<G, H, 0, stream>>>(question_tokens, w, qatt, pooled_sum);

    const int nblocks = 1024;                    // 4096 waves, contiguous chunks
    const int waves   = nblocks * (256 / 64);
    const int chunk   = (E + waves - 1) / waves;
    k_main<<<nblocks, 256, 0, stream>>>(edge_tokens, edge_batch, selected,
                                        u, qatt, att_raw, pooled_sum, E, chunk);

    k_seg <<<G, 256, 0, stream>>>(edge_batch, selected, att_raw,
                                  edge_logits, gcount, E);
    k_pool<<<G, 256, 0, stream>>>(pooled_sum, gcount, question_tokens, W_edge,
                                  ln_g, ln_b, W1, b1, W2, b2,
                                  pooled_out, stop_out);
}

// Round 3
// 766.041 us; speedup vs baseline: 1.1288x; 1.0705x over previous
//
#include <hip/hip_runtime.h>
#include <math.h>

#define H   256
#define H2  512
#define FRONTIER_BONUS 0.5f
#define LN_EPS   1e-5f
#define F32_EPS  1.1920929e-07f   // jnp.finfo(float32).eps

typedef float v4f __attribute__((ext_vector_type(4)));

// ---------------------------------------------------------------------------
__device__ __forceinline__ float block_sum_256(float v, float* sbuf) {
    int tid = threadIdx.x;
    sbuf[tid] = v; __syncthreads();
    for (int s = 128; s > 0; s >>= 1) {
        if (tid < s) sbuf[tid] += sbuf[tid + s];
        __syncthreads();
    }
    float r = sbuf[0]; __syncthreads();
    return r;
}

__device__ __forceinline__ float block_max_256(float v, float* sbuf) {
    int tid = threadIdx.x;
    sbuf[tid] = v; __syncthreads();
    for (int s = 128; s > 0; s >>= 1) {
        if (tid < s) sbuf[tid] = fmaxf(sbuf[tid], sbuf[tid + s]);
        __syncthreads();
    }
    float r = sbuf[0]; __syncthreads();
    return r;
}

__device__ __forceinline__ float wave_sum(float p) {
    #pragma unroll
    for (int off = 1; off < 64; off <<= 1) p += __shfl_xor(p, off, 64);
    return p;   // all lanes hold the total
}

// ---------------------------------------------------------------------------
// Prologue (G+1 blocks):
//   block g<G : pooled_sum[g,:]=0 ; qatt[g] = q[g,:] . (att_vec @ W_query)
//              (w recomputed per block — 256 FMA/thread from L2-hot W_query)
//   block G   : u = att_vec @ W_edge
// ---------------------------------------------------------------------------
__global__ __launch_bounds__(256) void k_pro(const float* __restrict__ W_edge,
                                             const float* __restrict__ W_query,
                                             const float* __restrict__ att_vec,
                                             const float* __restrict__ q,
                                             float* __restrict__ u,
                                             float* __restrict__ qatt,
                                             float* __restrict__ pooled_sum,
                                             int G) {
    __shared__ float sbuf[256];
    int g = blockIdx.x, tid = threadIdx.x;
    if (g == G) {                       // u = att_vec @ W_edge
        float acc = 0.f;
        #pragma unroll 8
        for (int i = 0; i < H; ++i) acc += att_vec[i] * W_edge[i * H + tid];
        u[tid] = acc;
        return;
    }
    pooled_sum[(size_t)g * H + tid] = 0.f;
    float wv = 0.f;
    #pragma unroll 8
    for (int i = 0; i < H; ++i) wv += att_vec[i] * W_query[i * H + tid];
    float v = q[(size_t)g * H + tid] * wv;
    float s = block_sum_256(v, sbuf);
    if (tid == 0) qatt[g] = s;
}

// ---------------------------------------------------------------------------
// Main pass: one streaming read of edge_tokens (512 MB). One wave per
// contiguous edge chunk; branch-free runs of <=64 edges via __ballot;
// butterfly shfl dot; pooled accumulator flushed at graph boundaries.
// ---------------------------------------------------------------------------
__global__ __launch_bounds__(256) void k_main(const float* __restrict__ edge_tokens,
                                              const int*   __restrict__ edge_batch,
                                              const int*   __restrict__ selected,
                                              const float* __restrict__ u,
                                              const float* __restrict__ qatt,
                                              float* __restrict__ att_raw,
                                              float* __restrict__ pooled_sum,
                                              int E, int chunk) {
    int wave = (blockIdx.x * blockDim.x + threadIdx.x) >> 6;
    int lane = threadIdx.x & 63;
    int e0 = wave * chunk;
    if (e0 >= E) return;
    int e1 = e0 + chunk; if (e1 > E) e1 = E;

    const v4f u4 = ((const v4f*)u)[lane];
    const v4f* et = (const v4f*)edge_tokens;
    v4f acc = (v4f)(0.f);
    int cur = edge_batch[e0];

    int e = e0;
    while (e < e1) {
        int n = e1 - e; if (n > 64) n = 64;
        int idx = e + ((lane < n) ? lane : (n - 1));
        int gb  = edge_batch[idx];                 // coalesced window load
        int sel = selected[idx];
        int g0  = __shfl(gb, 0, 64);               // wave-uniform graph id
        unsigned long long diff = __ballot(gb != g0);
        int run = n;
        if (diff) { int f = (int)__ffsll(diff) - 1; if (f < run) run = f; }

        if (g0 != cur) {                           // flush pooled accumulator
            float* dst = pooled_sum + (size_t)cur * H + lane * 4;
            atomicAdd(dst + 0, acc.x); atomicAdd(dst + 1, acc.y);
            atomicAdd(dst + 2, acc.z); atomicAdd(dst + 3, acc.w);
            acc = (v4f)(0.f);
            cur = g0;
        }
        float qa = qatt[g0];                       // wave-uniform
        float my_att = 0.f;

        #pragma unroll 4
        for (int i = 0; i < run; ++i) {
            v4f t = __builtin_nontemporal_load(&et[(size_t)(e + i) * 64 + lane]);
            acc += t;
            float p = fmaf(t.x, u4.x, fmaf(t.y, u4.y, fmaf(t.z, u4.z, t.w * u4.w)));
            p = wave_sum(p);
            if (i == lane) my_att = p;             // lane i keeps edge e+i
        }

        if (lane < run) {                          // coalesced att_raw store
            float a = my_att + qa;
            a = (a > 0.f) ? a : 0.2f * a;          // LeakyReLU(0.2)
            if (sel == 0) a += FRONTIER_BONUS;
            att_raw[e + lane] = a;
        }
        e += run;
    }
    float* dst = pooled_sum + (size_t)cur * H + lane * 4;
    atomicAdd(dst + 0, acc.x); atomicAdd(dst + 1, acc.y);
    atomicAdd(dst + 2, acc.z); atomicAdd(dst + 3, acc.w);
}

// ---------------------------------------------------------------------------
// Epilogue (G blocks): segment softmax -> edge_logits, then
// pooled = (pooled_sum @ W_edge.T)/cnt, LayerNorm(concat) -> W1 -> GELU -> W2.
// ---------------------------------------------------------------------------
__global__ __launch_bounds__(256) void k_epi(const int*   __restrict__ edge_batch,
                                             const int*   __restrict__ selected,
                                             const float* __restrict__ att_raw,
                                             const float* __restrict__ pooled_sum,
                                             const float* __restrict__ q,
                                             const float* __restrict__ W_edge,
                                             const float* __restrict__ ln_g,
                                             const float* __restrict__ ln_b,
                                             const float* __restrict__ W1,
                                             const float* __restrict__ b1,
                                             const float* __restrict__ W2,
                                             const float* __restrict__ b2,
                                             float* __restrict__ edge_logits,
                                             float* __restrict__ pooled_out,
                                             float* __restrict__ stop_out,
                                             int E) {
    __shared__ int srange[2];
    __shared__ __align__(16) float sS[H];
    __shared__ __align__(16) float sP[H];
    __shared__ __align__(16) float sxn[H2];
    __shared__ __align__(16) float sgk[H];
    __shared__ float sbuf[256];
    int g = blockIdx.x, tid = threadIdx.x;
    int lane = tid & 63, wv = tid >> 6;            // 4 waves

    if (tid < 2) {                                 // both bounds in parallel
        int target = g + tid, lo = 0, hi = E;
        while (lo < hi) { int m = (lo + hi) >> 1;
                          if (edge_batch[m] < target) lo = m + 1; else hi = m; }
        srange[tid] = lo;
    }
    sS[tid] = pooled_sum[(size_t)g * H + tid];
    __syncthreads();
    int s = srange[0], t = srange[1];

    // ---- segment softmax -> edge_logits
    float m = -INFINITY;
    for (int e = s + tid; e < t; e += 256) m = fmaxf(m, att_raw[e]);
    m = block_max_256(m, sbuf);

    float ss = 0.f;
    for (int e = s + tid; e < t; e += 256)
        if (selected[e] == 0) ss += expf(att_raw[e] - m);
    ss = block_sum_256(ss, sbuf);
    float denom = fmaxf(ss, F32_EPS);

    for (int e = s + tid; e < t; e += 256) {
        float ex = (selected[e] == 0) ? expf(att_raw[e] - m) : 0.f;
        edge_logits[e] = logf(fmaxf(ex / denom, F32_EPS));
    }

    // ---- pooled GEMV: P[i] = (sS . W_edge[i,:]) / max(cnt,1)
    int   cnt = t - s;
    float inv = 1.f / (float)(cnt > 1 ? cnt : 1);
    v4f s4 = ((const v4f*)sS)[lane];
    for (int r = 0; r < 64; ++r) {
        int i = wv * 64 + r;
        v4f w4 = ((const v4f*)(W_edge + (size_t)i * H))[lane];
        float p = fmaf(w4.x, s4.x, fmaf(w4.y, s4.y, fmaf(w4.z, s4.z, w4.w * s4.w)));
        p = wave_sum(p);
        if (lane == 0) sP[i] = p * inv;
    }
    __syncthreads();
    float P = sP[tid];
    pooled_out[(size_t)g * H + tid] = P;

    // ---- LayerNorm over concat(P, q) (512 elems, 2 per thread)
    float x1 = q[(size_t)g * H + tid];
    float mu  = block_sum_256(P + x1, sbuf) * (1.f / (float)H2);
    float d0 = P - mu, d1 = x1 - mu;
    float var = block_sum_256(d0 * d0 + d1 * d1, sbuf) * (1.f / (float)H2);
    float rstd = rsqrtf(var + LN_EPS);
    sxn[tid]     = d0 * rstd * ln_g[tid]     + ln_b[tid];
    sxn[tid + H] = d1 * rstd * ln_g[tid + H] + ln_b[tid + H];
    __syncthreads();

    // ---- h1[k] = gelu(xn . W1[k,:] + b1[k]); stop = sum_k h1[k]*W2[k] + b2
    v4f xa = ((const v4f*)sxn)[lane];
    v4f xb = ((const v4f*)sxn)[lane + 64];
    for (int r = 0; r < 64; ++r) {
        int k = wv * 64 + r;
        const v4f* w1r = (const v4f*)(W1 + (size_t)k * H2);
        v4f a0 = w1r[lane], a1 = w1r[lane + 64];
        float p = fmaf(a0.x, xa.x, fmaf(a0.y, xa.y, fmaf(a0.z, xa.z, a0.w * xa.w)))
                + fmaf(a1.x, xb.x, fmaf(a1.y, xb.y, fmaf(a1.z, xb.z, a1.w * xb.w)));
        p = wave_sum(p);
        if (lane == 0) {
            float a = p + b1[k];
            float ge = 0.5f * a * (1.f + erff(a * 0.70710678118654752f));
            sgk[k] = ge * W2[k];
        }
    }
    __syncthreads();
    float tot = block_sum_256(sgk[tid], sbuf);
    if (tid == 0) stop_out[g] = tot + b2[0];
}

// ---------------------------------------------------------------------------
extern "C" void kernel_launch(void* const* d_in, const int* in_sizes, int n_in,
                              void* d_out, int out_size, void* d_ws, size_t ws_size,
                              hipStream_t stream) {
    const float* edge_tokens     = (const float*)d_in[0];
    const float* question_tokens = (const float*)d_in[1];
    const int*   edge_batch      = (const int*)  d_in[2];
    const int*   selected        = (const int*)  d_in[3];
    const float* W_edge          = (const float*)d_in[4];
    const float* W_query         = (const float*)d_in[5];
    const float* att_vec         = (const float*)d_in[6];
    const float* ln_g            = (const float*)d_in[7];
    const float* ln_b            = (const float*)d_in[8];
    const float* W1              = (const float*)d_in[9];
    const float* b1              = (const float*)d_in[10];
    const float* W2              = (const float*)d_in[11];
    const float* b2              = (const float*)d_in[12];

    const int E = in_sizes[2];          // 500000
    const int G = in_sizes[1] / H;      // 256

    float* out         = (float*)d_out;
    float* edge_logits = out;           // [E]
    float* stop_out    = out + E;       // [G]
    float* pooled_out  = out + E + G;   // [G*H]

    float* ws         = (float*)d_ws;
    float* att_raw    = ws;                              // E
    float* pooled_sum = ws + E;                          // G*H
    float* u          = pooled_sum + (size_t)G * H;      // H
    float* qatt       = u + H;                           // G

    k_pro<<<G + 1, 256, 0, stream>>>(W_edge, W_query, att_vec, question_tokens,
                                     u, qatt, pooled_sum, G);

    const int nblocks = 2048;                    // 8192 waves, contiguous chunks
    const int waves   = nblocks * (256 / 64);
    const int chunk   = (E + waves - 1) / waves;
    k_main<<<nblocks, 256, 0, stream>>>(edge_tokens, edge_batch, selected,
                                        u, qatt, att_raw, pooled_sum, E, chunk);

    k_epi<<<G, 256, 0, stream>>>(edge_batch, selected, att_raw, pooled_sum,
                                 question_tokens, W_edge, ln_g, ln_b,
                                 W1, b1, W2, b2,
                                 edge_logits, pooled_out, stop_out, E);
}